// Round 11
// baseline (262.810 us; speedup 1.0000x reference)
//
#include <hip/hip_runtime.h>

#define HIDDEN 64
#define HALFD  32
#define VOCAB  64
#define BATCH  256
#define SEQLEN 2048

#define WOFF    16384          // float offset of W-pack region in ws
#define WSTRIDE 40             // floats per chunk pack (36 + 4 pad, 16B aligned)

#define RLF(v, sl) __int_as_float(__builtin_amdgcn_readlane(__float_as_int(v), (sl)))
#define RLI(v, sl) __builtin_amdgcn_readlane((v), (sl))
#define GIX(j,m) (((j)==0?0:(j)==1?7:(j)==2?13:(j)==3?18:(j)==4?22:(j)==5?25:27) + (m) - (j) - 1)
#define OM(m) (((m)*((m)+1))>>1)

// ---------------------------------------------------------------------------
// Kernel 1: per-token vocab tables (unchanged).
//   ws[0    ..2047]  ks_voc [64][32]  (normalized hs)
//   ws[2048 ..4095]  ke_voc [64][32]  (normalized he)
//   ws[4096 ..6143]  vs_voc [64][32]  (raw hs)
//   ws[6144 ..8191]  ve_voc [64][32]  (raw he)
//   ws[8192 ..16383] Gs,Ge [2][64][64]
//   ws[16384..]      W-packs [B][2][256][40]   (written by wbuild_kernel)
// ---------------------------------------------------------------------------
__global__ __launch_bounds__(64) void vocab_kernel(
    const float* __restrict__ embed, const float* __restrict__ W1, const float* __restrict__ b1,
    const float* __restrict__ W2, const float* __restrict__ b2,
    const float* __restrict__ ln_g, const float* __restrict__ ln_b,
    const float* __restrict__ Ws, const float* __restrict__ bs,
    const float* __restrict__ We, const float* __restrict__ be,
    float* __restrict__ ws)
{
    const int v = blockIdx.x;
    const int tid = threadIdx.x;

    __shared__ float e_s[64];
    __shared__ float a1_s[128];
    __shared__ float h_s[64];

    e_s[tid] = embed[v * 64 + tid];
    __syncthreads();

    float acc0 = b1[tid], acc1 = b1[tid + 64];
    #pragma unroll 8
    for (int m = 0; m < 64; ++m) {
        float ev = e_s[m];
        acc0 = fmaf(ev, W1[tid * 64 + m], acc0);
        acc1 = fmaf(ev, W1[(tid + 64) * 64 + m], acc1);
    }
    a1_s[tid]      = fmaxf(acc0, 0.0f);
    a1_s[tid + 64] = fmaxf(acc1, 0.0f);
    __syncthreads();

    float ff = b2[tid];
    #pragma unroll 8
    for (int m = 0; m < 128; ++m) ff = fmaf(a1_s[m], W2[tid * 128 + m], ff);
    float x = e_s[tid] + ff;

    float s = x, s2 = x * x;
    #pragma unroll
    for (int off = 32; off >= 1; off >>= 1) {
        s  += __shfl_xor(s,  off, 64);
        s2 += __shfl_xor(s2, off, 64);
    }
    float mu  = s * (1.0f / 64.0f);
    float var = s2 * (1.0f / 64.0f) - mu * mu;
    float hval = (x - mu) * rsqrtf(var + 1e-5f) * ln_g[tid] + ln_b[tid];
    h_s[tid] = hval;
    __syncthreads();

    const int j = tid & 31;
    const bool is_s = tid < 32;
    const float* W = is_s ? Ws : We;
    float acc = is_s ? bs[j] : be[j];
    #pragma unroll 8
    for (int m = 0; m < 64; ++m) acc = fmaf(h_s[m], W[j * 64 + m], acc);

    float n2 = acc * acc;
    #pragma unroll
    for (int off = 16; off >= 1; off >>= 1) n2 += __shfl_xor(n2, off, 64);
    float norm = sqrtf(n2);
    float kn = acc / fmaxf(norm, 1e-12f);

    const int base = v * 32 + j;
    if (is_s) { ws[base]        = kn; ws[4096 + base] = acc; }
    else      { ws[2048 + base] = kn; ws[6144 + base] = acc; }
}

// ---------------------------------------------------------------------------
// Kernel 1b: Gram tables (unchanged).
// ---------------------------------------------------------------------------
__global__ __launch_bounds__(256) void gram_kernel(float* __restrict__ ws)
{
    const int w = blockIdx.x;
    const int tid = threadIdx.x;
    __shared__ float k_s[2048];
    const float* kb = ws + w * 2048;
    for (int i = tid; i < 2048; i += 256) k_s[i] = kb[i];
    __syncthreads();
    const int a  = tid >> 2;
    const int b0 = (tid & 3) << 4;
    float* Gw = ws + 8192 + w * 4096 + a * 64;
    for (int bb = 0; bb < 16; ++bb) {
        const int bcol = b0 + bb;
        float acc = 0.f;
        #pragma unroll
        for (int m = 0; m < 32; ++m) acc = fmaf(k_s[a * 32 + m], k_s[bcol * 32 + m], acc);
        Gw[bcol] = acc;
    }
}

// shared W-build routine (verbatim R9 math)
static __device__ __forceinline__ void build_wpack(
    const int* tj, float fb, float invL, bool is_e, bool is_last, float* Wp,
    const float* __restrict__ Gg)
{
    float f[8];
    #pragma unroll
    for (int j = 0; j < 8; ++j) f[j] = is_e ? (fb + (float)j * invL) : 1.0f;
    if (is_last) f[7] = 0.0f;     // position 2047 is the query, not a write

    float g[28];
    #pragma unroll
    for (int j = 0; j < 7; ++j)
        #pragma unroll
        for (int m = j + 1; m < 8; ++m) g[GIX(j, m)] = Gg[tj[j] * 64 + tj[m]];

    #pragma unroll
    for (int m = 0; m < 8; ++m) {
        float col[8];
        col[m] = f[m];
        #pragma unroll
        for (int j = 6; j >= 0; --j) {
            if (j < m) {
                float acc = 0.0f;
                #pragma unroll
                for (int p = 1; p < 8; ++p)
                    if (p > j && p <= m) acc = fmaf(g[GIX(j, p)], col[p], acc);
                col[j] = -f[j] * acc;
            }
        }
        #pragma unroll
        for (int j = 0; j < 8; ++j)
            if (j <= m) Wp[OM(m) + j] = col[j];
    }
}

// ---------------------------------------------------------------------------
// Kernel 1c: W-pack build, fully parallel (256 blocks x 128 thr, 4 packs/lane).
// Separate kernel => kernel-boundary coherence: the scan can read W as pure
// read-only uniform data (s_load-eligible). R10 post-mortem: building W in
// the scan itself forced a same-kernel global round-trip that the compiler
// rematerialized (VGPR 56) and that hit HBM.
// ---------------------------------------------------------------------------
__global__ __launch_bounds__(128) void wbuild_kernel(
    const int* __restrict__ seq, float* __restrict__ ws)
{
    const int b    = blockIdx.x;
    const int tid  = threadIdx.x;
    const int w    = tid >> 6;
    const int lane = tid & 63;
    const bool is_e = (w == 1);

    const float* Gg  = ws + 8192 + w * 4096;
    float*       wsW = ws + WOFF + ((size_t)(b * 2 + w)) * (256 * WSTRIDE);
    const int*   sq  = seq + b * SEQLEN;
    const float invL = 1.0f / (float)SEQLEN;

    #pragma unroll
    for (int qq = 0; qq < 4; ++qq) {
        const int c = lane + (qq << 6);
        int tj[8];
        #pragma unroll
        for (int j = 0; j < 8; ++j) tj[j] = sq[c * 8 + j];
        float Wp[36];
        build_wpack(tj, (float)(8 * c + 1) * invL, invL, is_e, c == 255, Wp, Gg);
        float4* dst = (float4*)&wsW[c * WSTRIDE];
        #pragma unroll
        for (int i = 0; i < 9; ++i)
            dst[i] = make_float4(Wp[4*i], Wp[4*i+1], Wp[4*i+2], Wp[4*i+3]);
    }
}

struct Chunk {
    int   tokv;      // lane-vector: tok[c*8 + (lane&7)]  (bpermute index)
    int   tk[8];     // uniform tokens of this chunk (SGPR-resident)
    float grow[8];   // G[tok_j][lane]
    float W[36];     // packed upper-tri solve matrix (uniform, SGPR-eligible)
};

// ---------------------------------------------------------------------------
// Kernel 2 (primary): Gram-space backward sweep, scalar-pipe W/tokens.
// Loop traffic: 1 ds_bpermute (the ONLY DS op), uniform W/token loads
// (s_load -> SGPRs; scalar pipe), 8+1 lane-indexed VMEM loads (grow, tokv).
// Solve/u-update/wacc all VALU with SGPR operands.
// ---------------------------------------------------------------------------
__global__ __launch_bounds__(128) void scan_s_kernel(
    const int* __restrict__ seq, const float* __restrict__ ws,
    const float* __restrict__ Wrp, const float* __restrict__ brp,
    const float* __restrict__ Wo, const float* __restrict__ bo,
    float* __restrict__ out)
{
    const int b    = blockIdx.x;
    const int tid  = threadIdx.x;        // 0..127
    const int w    = tid >> 6;           // wave: 0 = s-branch, 1 = e-branch
    const int lane = tid & 63;
    const int l7   = lane & 7;

    __shared__ float wacc_s[2][64];
    __shared__ float r_s[64];
    __shared__ float t1_s[64];

    const float* Gg  = ws + 8192 + w * 4096;
    const float* wsW = ws + WOFF + ((size_t)(b * 2 + w)) * (256 * WSTRIDE);
    const int*   sq  = seq + b * SEQLEN;

    Chunk A, B;
    float u, waccv = 0.0f;

    // prologue: chunk 255 fully, chunk 254 lane-tokens
    #pragma unroll
    for (int j = 0; j < 8; ++j) A.tk[j] = sq[2040 + j];      // uniform -> s_load
    A.tokv = sq[2040 + l7];
    #pragma unroll
    for (int j = 0; j < 8; ++j) A.grow[j] = Gg[A.tk[j] * 64 + lane];
    {
        const float4* wsrc = (const float4*)&wsW[255 * WSTRIDE];
        #pragma unroll
        for (int i = 0; i < 9; ++i) {
            float4 v = wsrc[i];
            A.W[4*i] = v.x; A.W[4*i+1] = v.y; A.W[4*i+2] = v.z; A.W[4*i+3] = v.w;
        }
    }
    B.tokv = sq[2032 + l7];
    u = Gg[A.tk[7] * 64 + lane];     // query token = position 2047

    auto body = [&](Chunk& cur, Chunk& nxt, int c) {
        // chain anchor: the loop's only DS op
        float bp = __shfl(u, cur.tokv, 64);

        // prefetch chunk c-1: uniform tokens + W (scalar pipe), grow (VMEM)
        const int cm1 = (c > 0) ? c - 1 : 0;
        const int cm2 = (c > 1) ? c - 2 : 0;
        #pragma unroll
        for (int j = 0; j < 8; ++j) nxt.tk[j] = sq[cm1 * 8 + j];   // uniform
        #pragma unroll
        for (int j = 0; j < 8; ++j) nxt.grow[j] = Gg[nxt.tk[j] * 64 + lane];
        {
            const float4* wsrc = (const float4*)&wsW[cm1 * WSTRIDE];
            #pragma unroll
            for (int i = 0; i < 9; ++i) {
                float4 v = wsrc[i];
                nxt.W[4*i] = v.x; nxt.W[4*i+1] = v.y; nxt.W[4*i+2] = v.z; nxt.W[4*i+3] = v.w;
            }
        }
        int tokv2 = sq[cm2 * 8 + l7];

        float t0 = RLF(bp, 0), t1 = RLF(bp, 1), t2 = RLF(bp, 2), t3 = RLF(bp, 3);
        float t4 = RLF(bp, 4), t5 = RLF(bp, 5), t6 = RLF(bp, 6), t7 = RLF(bp, 7);

        // s = W t  (36 independent FMAs, depth <= 4; W operands SGPR)
        const float* W = cur.W;
        float s7 = W[35] * t7;
        float s6 = fmaf(W[27], t6, W[34] * t7);
        float s5 = fmaf(W[20], t5, W[26] * t6) + W[33] * t7;
        float s4 = fmaf(W[14], t4, W[19] * t5) + fmaf(W[25], t6, W[32] * t7);
        float s3 = fmaf(W[9],  t3, W[13] * t4) + fmaf(W[18], t5, fmaf(W[24], t6, W[31] * t7));
        float s2 = fmaf(W[5],  t2, W[8]  * t3) + fmaf(W[12], t4, W[17] * t5) + fmaf(W[23], t6, W[30] * t7);
        float s1 = fmaf(W[2],  t1, W[4]  * t2) + fmaf(W[7],  t3, W[11] * t4) + fmaf(W[16], t5, fmaf(W[22], t6, W[29] * t7));
        float s0 = fmaf(W[0],  t0, W[1]  * t1) + fmaf(W[3],  t2, W[6]  * t3) + fmaf(W[10], t4, W[15] * t5) + fmaf(W[21], t6, W[28] * t7);

        // u[a] -= sum_j s_j * G[tok_j][a]
        float dA = fmaf(cur.grow[0], s0, fmaf(cur.grow[1], s1, fmaf(cur.grow[2], s2, cur.grow[3] * s3)));
        float dB = fmaf(cur.grow[4], s4, fmaf(cur.grow[5], s5, fmaf(cur.grow[6], s6, cur.grow[7] * s7)));
        u -= (dA + dB);

        // wacc[tok_j] += s_j  (lane = token; tk in SGPR)
        waccv += (lane == cur.tk[0]) ? s0 : 0.0f;
        waccv += (lane == cur.tk[1]) ? s1 : 0.0f;
        waccv += (lane == cur.tk[2]) ? s2 : 0.0f;
        waccv += (lane == cur.tk[3]) ? s3 : 0.0f;
        waccv += (lane == cur.tk[4]) ? s4 : 0.0f;
        waccv += (lane == cur.tk[5]) ? s5 : 0.0f;
        waccv += (lane == cur.tk[6]) ? s6 : 0.0f;
        waccv += (lane == cur.tk[7]) ? s7 : 0.0f;

        cur.tokv = tokv2;
    };

    for (int c = 255; c >= 1; c -= 2) {
        body(A, B, c);
        body(B, A, c - 1);
    }

    wacc_s[w][lane] = waccv;
    __syncthreads();

    if (tid < 64) {
        const int w2  = tid >> 5;
        const int rho = tid & 31;
        const float* vv = ws + 4096 + w2 * 2048;
        const float* wa = &wacc_s[w2][0];
        float acc = 0.0f;
        #pragma unroll 8
        for (int tok = 0; tok < 64; ++tok) acc = fmaf(wa[tok], vv[tok * 32 + rho], acc);
        r_s[tid] = acc;
    }
    __syncthreads();

    if (tid < 64) {
        float acc = brp[tid];
        #pragma unroll 8
        for (int m = 0; m < 64; ++m) acc = fmaf(Wrp[tid * 64 + m], r_s[m], acc);
        t1_s[tid] = acc;
    }
    __syncthreads();
    if (tid < 64) {
        float acc = bo[tid];
        #pragma unroll 8
        for (int m = 0; m < 64; ++m) acc = fmaf(Wo[tid * 64 + m], t1_s[m], acc);
        out[b * 64 + tid] = acc;
    }
}

// ---------------------------------------------------------------------------
// Kernel 2 (fallback, ws too small for W region): R9 LDS-Wtab version.
// ---------------------------------------------------------------------------
__global__ __launch_bounds__(128) void scan_lds_kernel(
    const int* __restrict__ seq, const float* __restrict__ ws,
    const float* __restrict__ Wrp, const float* __restrict__ brp,
    const float* __restrict__ Wo, const float* __restrict__ bo,
    float* __restrict__ out)
{
    const int b    = blockIdx.x;
    const int tid  = threadIdx.x;
    const int w    = tid >> 6;
    const int lane = tid & 63;
    const int l7   = lane & 7;
    const bool is_e = (w == 1);

    __shared__ __align__(16) float Wtab[2 * 256 * 36];
    __shared__ __align__(16) int   toklds[SEQLEN];
    __shared__ float wacc_s[2][64];
    __shared__ float r_s[64];
    __shared__ float t1_s[64];

    const float* Gg     = ws + 8192 + w * 4096;
    float*       Wtab_w = Wtab + w * (256 * 36);

    {
        const int4* sq4 = (const int4*)(seq + b * SEQLEN);
        int4* tl = (int4*)toklds;
        #pragma unroll
        for (int i = 0; i < 4; ++i) tl[tid + i * 128] = sq4[tid + i * 128];
    }
    __syncthreads();

    {
        const float invL = 1.0f / (float)SEQLEN;
        #pragma unroll
        for (int qq = 0; qq < 4; ++qq) {
            const int c = lane + (qq << 6);
            int tj[8];
            #pragma unroll
            for (int j = 0; j < 8; ++j) tj[j] = toklds[c * 8 + j];
            float Wp[36];
            build_wpack(tj, (float)(8 * c + 1) * invL, invL, is_e, c == 255, Wp, Gg);
            float4* dst = (float4*)&Wtab_w[c * 36];
            #pragma unroll
            for (int i = 0; i < 9; ++i)
                dst[i] = make_float4(Wp[4*i], Wp[4*i+1], Wp[4*i+2], Wp[4*i+3]);
        }
    }
    __syncthreads();

    Chunk A, B;
    float u, waccv = 0.0f;

    A.tokv = toklds[2040 + l7];
    #pragma unroll
    for (int j = 0; j < 8; ++j) A.tk[j] = RLI(A.tokv, j);
    #pragma unroll
    for (int j = 0; j < 8; ++j) A.grow[j] = Gg[A.tk[j] * 64 + lane];
    {
        const float4* wsrc = (const float4*)&Wtab_w[255 * 36];
        #pragma unroll
        for (int i = 0; i < 9; ++i) {
            float4 v = wsrc[i];
            A.W[4*i] = v.x; A.W[4*i+1] = v.y; A.W[4*i+2] = v.z; A.W[4*i+3] = v.w;
        }
    }
    B.tokv = toklds[2032 + l7];
    u = Gg[A.tk[7] * 64 + lane];

    auto body = [&](Chunk& cur, Chunk& nxt, int c) {
        float bp = __shfl(u, cur.tokv, 64);
        const int cm1 = (c > 0) ? c - 1 : 0;
        const int cm2 = (c > 1) ? c - 2 : 0;
        #pragma unroll
        for (int j = 0; j < 8; ++j) nxt.tk[j] = RLI(nxt.tokv, j);
        #pragma unroll
        for (int j = 0; j < 8; ++j) nxt.grow[j] = Gg[nxt.tk[j] * 64 + lane];
        {
            const float4* wsrc = (const float4*)&Wtab_w[cm1 * 36];
            #pragma unroll
            for (int i = 0; i < 9; ++i) {
                float4 v = wsrc[i];
                nxt.W[4*i] = v.x; nxt.W[4*i+1] = v.y; nxt.W[4*i+2] = v.z; nxt.W[4*i+3] = v.w;
            }
        }
        int tokv2 = toklds[cm2 * 8 + l7];

        float t0 = RLF(bp, 0), t1 = RLF(bp, 1), t2 = RLF(bp, 2), t3 = RLF(bp, 3);
        float t4 = RLF(bp, 4), t5 = RLF(bp, 5), t6 = RLF(bp, 6), t7 = RLF(bp, 7);

        const float* W = cur.W;
        float s7 = W[35] * t7;
        float s6 = fmaf(W[27], t6, W[34] * t7);
        float s5 = fmaf(W[20], t5, W[26] * t6) + W[33] * t7;
        float s4 = fmaf(W[14], t4, W[19] * t5) + fmaf(W[25], t6, W[32] * t7);
        float s3 = fmaf(W[9],  t3, W[13] * t4) + fmaf(W[18], t5, fmaf(W[24], t6, W[31] * t7));
        float s2 = fmaf(W[5],  t2, W[8]  * t3) + fmaf(W[12], t4, W[17] * t5) + fmaf(W[23], t6, W[30] * t7);
        float s1 = fmaf(W[2],  t1, W[4]  * t2) + fmaf(W[7],  t3, W[11] * t4) + fmaf(W[16], t5, fmaf(W[22], t6, W[29] * t7));
        float s0 = fmaf(W[0],  t0, W[1]  * t1) + fmaf(W[3],  t2, W[6]  * t3) + fmaf(W[10], t4, W[15] * t5) + fmaf(W[21], t6, W[28] * t7);

        float dA = fmaf(cur.grow[0], s0, fmaf(cur.grow[1], s1, fmaf(cur.grow[2], s2, cur.grow[3] * s3)));
        float dB = fmaf(cur.grow[4], s4, fmaf(cur.grow[5], s5, fmaf(cur.grow[6], s6, cur.grow[7] * s7)));
        u -= (dA + dB);

        waccv += (lane == cur.tk[0]) ? s0 : 0.0f;
        waccv += (lane == cur.tk[1]) ? s1 : 0.0f;
        waccv += (lane == cur.tk[2]) ? s2 : 0.0f;
        waccv += (lane == cur.tk[3]) ? s3 : 0.0f;
        waccv += (lane == cur.tk[4]) ? s4 : 0.0f;
        waccv += (lane == cur.tk[5]) ? s5 : 0.0f;
        waccv += (lane == cur.tk[6]) ? s6 : 0.0f;
        waccv += (lane == cur.tk[7]) ? s7 : 0.0f;

        cur.tokv = tokv2;
    };

    for (int c = 255; c >= 1; c -= 2) {
        body(A, B, c);
        body(B, A, c - 1);
    }

    wacc_s[w][lane] = waccv;
    __syncthreads();

    if (tid < 64) {
        const int w2  = tid >> 5;
        const int rho = tid & 31;
        const float* vv = ws + 4096 + w2 * 2048;
        const float* wa = &wacc_s[w2][0];
        float acc = 0.0f;
        #pragma unroll 8
        for (int tok = 0; tok < 64; ++tok) acc = fmaf(wa[tok], vv[tok * 32 + rho], acc);
        r_s[tid] = acc;
    }
    __syncthreads();

    if (tid < 64) {
        float acc = brp[tid];
        #pragma unroll 8
        for (int m = 0; m < 64; ++m) acc = fmaf(Wrp[tid * 64 + m], r_s[m], acc);
        t1_s[tid] = acc;
    }
    __syncthreads();
    if (tid < 64) {
        float acc = bo[tid];
        #pragma unroll 8
        for (int m = 0; m < 64; ++m) acc = fmaf(Wo[tid * 64 + m], t1_s[m], acc);
        out[b * 64 + tid] = acc;
    }
}

extern "C" void kernel_launch(void* const* d_in, const int* in_sizes, int n_in,
                              void* d_out, int out_size, void* d_ws, size_t ws_size,
                              hipStream_t stream)
{
    const int*   seq   = (const int*)  d_in[0];
    const float* embed = (const float*)d_in[1];
    const float* W1    = (const float*)d_in[2];
    const float* b1    = (const float*)d_in[3];
    const float* W2    = (const float*)d_in[4];
    const float* b2    = (const float*)d_in[5];
    const float* ln_g  = (const float*)d_in[6];
    const float* ln_b  = (const float*)d_in[7];
    const float* Ws    = (const float*)d_in[8];
    const float* bs    = (const float*)d_in[9];
    const float* We    = (const float*)d_in[10];
    const float* be    = (const float*)d_in[11];
    const float* Wrp   = (const float*)d_in[12];
    const float* brp   = (const float*)d_in[13];
    const float* Wo    = (const float*)d_in[14];
    const float* bo    = (const float*)d_in[15];
    float* ws  = (float*)d_ws;
    float* out = (float*)d_out;

    hipLaunchKernelGGL(vocab_kernel, dim3(VOCAB), dim3(64), 0, stream,
                       embed, W1, b1, W2, b2, ln_g, ln_b, Ws, bs, We, be, ws);
    hipLaunchKernelGGL(gram_kernel, dim3(2), dim3(256), 0, stream, ws);

    const size_t need = (size_t)(WOFF + BATCH * 2 * 256 * WSTRIDE) * sizeof(float);
    if (ws_size >= need) {
        hipLaunchKernelGGL(wbuild_kernel, dim3(BATCH), dim3(128), 0, stream, seq, ws);
        hipLaunchKernelGGL(scan_s_kernel, dim3(BATCH), dim3(128), 0, stream,
                           seq, ws, Wrp, brp, Wo, bo, out);
    } else {
        hipLaunchKernelGGL(scan_lds_kernel, dim3(BATCH), dim3(128), 0, stream,
                           seq, ws, Wrp, brp, Wo, bo, out);
    }
}

// Round 12
// 255.540 us; speedup vs baseline: 1.0285x; 1.0285x over previous
//
#include <hip/hip_runtime.h>

#define HIDDEN 64
#define HALFD  32
#define VOCAB  64
#define BATCH  256
#define SEQLEN 2048

#define RLF(v, sl) __int_as_float(__builtin_amdgcn_readlane(__float_as_int(v), (sl)))

// ---------------------------------------------------------------------------
// Kernel 1: per-token vocab tables (unchanged).
//   ws[0    ..2047]  ks_voc [64][32]  (normalized hs)
//   ws[2048 ..4095]  ke_voc [64][32]  (normalized he)
//   ws[4096 ..6143]  vs_voc [64][32]  (raw hs)
//   ws[6144 ..8191]  ve_voc [64][32]  (raw he)
//   ws[8192 ..16383] Gs,Ge [2][64][64]
// ---------------------------------------------------------------------------
__global__ __launch_bounds__(64) void vocab_kernel(
    const float* __restrict__ embed, const float* __restrict__ W1, const float* __restrict__ b1,
    const float* __restrict__ W2, const float* __restrict__ b2,
    const float* __restrict__ ln_g, const float* __restrict__ ln_b,
    const float* __restrict__ Ws, const float* __restrict__ bs,
    const float* __restrict__ We, const float* __restrict__ be,
    float* __restrict__ ws)
{
    const int v = blockIdx.x;
    const int tid = threadIdx.x;

    __shared__ float e_s[64];
    __shared__ float a1_s[128];
    __shared__ float h_s[64];

    e_s[tid] = embed[v * 64 + tid];
    __syncthreads();

    float acc0 = b1[tid], acc1 = b1[tid + 64];
    #pragma unroll 8
    for (int m = 0; m < 64; ++m) {
        float ev = e_s[m];
        acc0 = fmaf(ev, W1[tid * 64 + m], acc0);
        acc1 = fmaf(ev, W1[(tid + 64) * 64 + m], acc1);
    }
    a1_s[tid]      = fmaxf(acc0, 0.0f);
    a1_s[tid + 64] = fmaxf(acc1, 0.0f);
    __syncthreads();

    float ff = b2[tid];
    #pragma unroll 8
    for (int m = 0; m < 128; ++m) ff = fmaf(a1_s[m], W2[tid * 128 + m], ff);
    float x = e_s[tid] + ff;

    float s = x, s2 = x * x;
    #pragma unroll
    for (int off = 32; off >= 1; off >>= 1) {
        s  += __shfl_xor(s,  off, 64);
        s2 += __shfl_xor(s2, off, 64);
    }
    float mu  = s * (1.0f / 64.0f);
    float var = s2 * (1.0f / 64.0f) - mu * mu;
    float hval = (x - mu) * rsqrtf(var + 1e-5f) * ln_g[tid] + ln_b[tid];
    h_s[tid] = hval;
    __syncthreads();

    const int j = tid & 31;
    const bool is_s = tid < 32;
    const float* W = is_s ? Ws : We;
    float acc = is_s ? bs[j] : be[j];
    #pragma unroll 8
    for (int m = 0; m < 64; ++m) acc = fmaf(h_s[m], W[j * 64 + m], acc);

    float n2 = acc * acc;
    #pragma unroll
    for (int off = 16; off >= 1; off >>= 1) n2 += __shfl_xor(n2, off, 64);
    float norm = sqrtf(n2);
    float kn = acc / fmaxf(norm, 1e-12f);

    const int base = v * 32 + j;
    if (is_s) { ws[base]        = kn; ws[4096 + base] = acc; }
    else      { ws[2048 + base] = kn; ws[6144 + base] = acc; }
}

// ---------------------------------------------------------------------------
// Kernel 1b: Gram tables (unchanged).
// ---------------------------------------------------------------------------
__global__ __launch_bounds__(256) void gram_kernel(float* __restrict__ ws)
{
    const int w = blockIdx.x;
    const int tid = threadIdx.x;
    __shared__ float k_s[2048];
    const float* kb = ws + w * 2048;
    for (int i = tid; i < 2048; i += 256) k_s[i] = kb[i];
    __syncthreads();
    const int a  = tid >> 2;
    const int b0 = (tid & 3) << 4;
    float* Gw = ws + 8192 + w * 4096 + a * 64;
    for (int bb = 0; bb < 16; ++bb) {
        const int bcol = b0 + bb;
        float acc = 0.f;
        #pragma unroll
        for (int m = 0; m < 32; ++m) acc = fmaf(k_s[a * 32 + m], k_s[bcol * 32 + m], acc);
        Gw[bcol] = acc;
    }
}

// ---------------------------------------------------------------------------
// Kernel 2: Gram-space backward sweep, table-free, end-of-body bpermute.
// R8 structure (triangular solve with g from readlanes of resident G rows,
// all tables in global/L1) with the two R8 flaws fixed:
//  (1) braw_{c-1} = shfl(u_c, tokv_{c-1}) issued at the END of body(c),
//      consumed at the TOP of body(c-1) -> a full body of slack; it is the
//      ONLY lgkm op in the loop.
//  (2) __launch_bounds__(128,1) + ~50-VGPR live set so token (2-ahead,
//      s_load) and G-row (2-ahead, VMEM) prefetches hoist instead of sink.
// ---------------------------------------------------------------------------
__global__ __launch_bounds__(128, 1) void scan_kernel(
    const int* __restrict__ seq, const float* __restrict__ ws,
    const float* __restrict__ Wrp, const float* __restrict__ brp,
    const float* __restrict__ Wo, const float* __restrict__ bo,
    float* __restrict__ out)
{
    const int b    = blockIdx.x;
    const int tid  = threadIdx.x;        // 0..127
    const int w    = tid >> 6;           // wave: 0 = s-branch, 1 = e-branch
    const int lane = tid & 63;
    const int l7   = lane & 7;
    const bool is_e = (w == 1);

    __shared__ float wacc_s[2][64];
    __shared__ float r_s[64];
    __shared__ float t1_s[64];

    const float* Gg = ws + 8192 + w * 4096;     // [64][64] Gram (L1/L2-hot, 16KB)
    const int*   sq = seq + b * SEQLEN;

    const float invL = 1.0f / (float)SEQLEN;

    // token pipeline: tkC = chunk c (in use), tkN = c-1, tkI = c-2 (incoming)
    int tkC[8], tkN[8], tkI[8];
    float grA[8], grB[8];                       // G rows ping-pong (c / c-1)

    #pragma unroll
    for (int j = 0; j < 8; ++j) tkC[j] = sq[2040 + j];   // chunk 255 (uniform)
    #pragma unroll
    for (int j = 0; j < 8; ++j) tkN[j] = sq[2032 + j];   // chunk 254
    #pragma unroll
    for (int j = 0; j < 8; ++j) grA[j] = Gg[tkC[j] * 64 + lane];
    #pragma unroll
    for (int j = 0; j < 8; ++j) grB[j] = Gg[tkN[j] * 64 + lane];
    int tokvC = sq[2040 + l7];                  // lane-tokens chunk 255
    int tokvN = sq[2032 + l7];                  // lane-tokens chunk 254

    float u = Gg[tkC[7] * 64 + lane];           // u_init: query tok = position 2047
    float braw = __shfl(u, tokvC, 64);          // t-raw for chunk 255
    float waccv = 0.0f;

    auto body = [&](int c, float (&gr)[8]) {
        const int cm2 = (c >= 2) ? (c - 2) : 0;
        // incoming token loads for chunk c-2 (scalar + one lane load)
        #pragma unroll
        for (int j = 0; j < 8; ++j) tkI[j] = sq[cm2 * 8 + j];
        int tokvI = sq[cm2 * 8 + l7];

        // ---- chain: t extraction (braw issued at end of previous body) ----
        float t0 = RLF(braw, 0), t1 = RLF(braw, 1), t2 = RLF(braw, 2), t3 = RLF(braw, 3);
        float t4 = RLF(braw, 4), t5 = RLF(braw, 5), t6 = RLF(braw, 6), t7 = RLF(braw, 7);

        // in-chunk Gram scalars from resident rows (off-chain, rows loaded 2 ago)
        float g01 = RLF(gr[0], tkC[1]), g02 = RLF(gr[0], tkC[2]), g03 = RLF(gr[0], tkC[3]);
        float g04 = RLF(gr[0], tkC[4]), g05 = RLF(gr[0], tkC[5]), g06 = RLF(gr[0], tkC[6]), g07 = RLF(gr[0], tkC[7]);
        float g12 = RLF(gr[1], tkC[2]), g13 = RLF(gr[1], tkC[3]), g14 = RLF(gr[1], tkC[4]);
        float g15 = RLF(gr[1], tkC[5]), g16 = RLF(gr[1], tkC[6]), g17 = RLF(gr[1], tkC[7]);
        float g23 = RLF(gr[2], tkC[3]), g24 = RLF(gr[2], tkC[4]), g25 = RLF(gr[2], tkC[5]);
        float g26 = RLF(gr[2], tkC[6]), g27 = RLF(gr[2], tkC[7]);
        float g34 = RLF(gr[3], tkC[4]), g35 = RLF(gr[3], tkC[5]), g36 = RLF(gr[3], tkC[6]), g37 = RLF(gr[3], tkC[7]);
        float g45 = RLF(gr[4], tkC[5]), g46 = RLF(gr[4], tkC[6]), g47 = RLF(gr[4], tkC[7]);
        float g56 = RLF(gr[5], tkC[6]), g57 = RLF(gr[5], tkC[7]);
        float g67 = RLF(gr[6], tkC[7]);

        // per-step factors (position 8c+7 of chunk 255 is the query: f7 = 0)
        float fb = (float)(8 * c + 1) * invL;
        float f0 = is_e ? fb            : 1.0f;
        float f1 = is_e ? fb +     invL : 1.0f;
        float f2 = is_e ? fb + 2 * invL : 1.0f;
        float f3 = is_e ? fb + 3 * invL : 1.0f;
        float f4 = is_e ? fb + 4 * invL : 1.0f;
        float f5 = is_e ? fb + 5 * invL : 1.0f;
        float f6 = is_e ? fb + 6 * invL : 1.0f;
        float f7 = (c == 255) ? 0.0f : (is_e ? fb + 7 * invL : 1.0f);

        // triangular WY adjoint solve (verbatim R7/R8 algebra)
        float s7 = f7 * t7;
        float s6 = f6 * (t6 - g67 * s7);
        float s5 = f5 * ((t5 - g57 * s7) - g56 * s6);
        float s4 = f4 * (((t4 - g47 * s7) - g46 * s6) - g45 * s5);
        float s3 = f3 * ((((t3 - g37 * s7) - g36 * s6) - g35 * s5) - g34 * s4);
        float s2 = f2 * (((((t2 - g27 * s7) - g26 * s6) - g25 * s5) - g24 * s4) - g23 * s3);
        float s1 = f1 * ((((((t1 - g17 * s7) - g16 * s6) - g15 * s5) - g14 * s4) - g13 * s3) - g12 * s2);
        float s0 = f0 * (((((((t0 - g07 * s7) - g06 * s6) - g05 * s5) - g04 * s4) - g03 * s3) - g02 * s2) - g01 * s1);

        // u[a] -= sum_j s_j * G[tok_j][a]
        float dA = fmaf(gr[0], s0, fmaf(gr[1], s1, fmaf(gr[2], s2, gr[3] * s3)));
        float dB = fmaf(gr[4], s4, fmaf(gr[5], s5, fmaf(gr[6], s6, gr[7] * s7)));
        u -= (dA + dB);

        // issue next braw IMMEDIATELY after u finalizes (full body of slack)
        braw = __shfl(u, tokvN, 64);

        // wacc[tok_j] += s_j  (lane = token; off-chain)
        waccv += (lane == tkC[0]) ? s0 : 0.0f;
        waccv += (lane == tkC[1]) ? s1 : 0.0f;
        waccv += (lane == tkC[2]) ? s2 : 0.0f;
        waccv += (lane == tkC[3]) ? s3 : 0.0f;
        waccv += (lane == tkC[4]) ? s4 : 0.0f;
        waccv += (lane == tkC[5]) ? s5 : 0.0f;
        waccv += (lane == tkC[6]) ? s6 : 0.0f;
        waccv += (lane == tkC[7]) ? s7 : 0.0f;

        // issue G rows for chunk c-2 into the retiring slot (consumed 2 bodies on)
        #pragma unroll
        for (int j = 0; j < 8; ++j) gr[j] = Gg[tkI[j] * 64 + lane];

        // rotate token pipeline
        #pragma unroll
        for (int j = 0; j < 8; ++j) { tkC[j] = tkN[j]; tkN[j] = tkI[j]; }
        tokvN = tokvI;
    };

    for (int c = 255; c >= 1; c -= 2) {
        body(c, grA);
        body(c - 1, grB);
    }

    wacc_s[w][lane] = waccv;
    __syncthreads();

    // r[w2][rho] = sum_tok wacc[w2][tok] * v[w2][tok][rho]  (v from global ws)
    if (tid < 64) {
        const int w2  = tid >> 5;
        const int rho = tid & 31;
        const float* vv = ws + 4096 + w2 * 2048;
        const float* wa = &wacc_s[w2][0];
        float acc = 0.0f;
        #pragma unroll 8
        for (int tok = 0; tok < 64; ++tok) acc = fmaf(wa[tok], vv[tok * 32 + rho], acc);
        r_s[tid] = acc;
    }
    __syncthreads();

    // out = (r @ Wrp.T + brp) @ Wo.T + bo
    if (tid < 64) {
        float acc = brp[tid];
        #pragma unroll 8
        for (int m = 0; m < 64; ++m) acc = fmaf(Wrp[tid * 64 + m], r_s[m], acc);
        t1_s[tid] = acc;
    }
    __syncthreads();
    if (tid < 64) {
        float acc = bo[tid];
        #pragma unroll 8
        for (int m = 0; m < 64; ++m) acc = fmaf(Wo[tid * 64 + m], t1_s[m], acc);
        out[b * 64 + tid] = acc;
    }
}

extern "C" void kernel_launch(void* const* d_in, const int* in_sizes, int n_in,
                              void* d_out, int out_size, void* d_ws, size_t ws_size,
                              hipStream_t stream)
{
    const int*   seq   = (const int*)  d_in[0];
    const float* embed = (const float*)d_in[1];
    const float* W1    = (const float*)d_in[2];
    const float* b1    = (const float*)d_in[3];
    const float* W2    = (const float*)d_in[4];
    const float* b2    = (const float*)d_in[5];
    const float* ln_g  = (const float*)d_in[6];
    const float* ln_b  = (const float*)d_in[7];
    const float* Ws    = (const float*)d_in[8];
    const float* bs    = (const float*)d_in[9];
    const float* We    = (const float*)d_in[10];
    const float* be    = (const float*)d_in[11];
    const float* Wrp   = (const float*)d_in[12];
    const float* brp   = (const float*)d_in[13];
    const float* Wo    = (const float*)d_in[14];
    const float* bo    = (const float*)d_in[15];
    float* ws  = (float*)d_ws;
    float* out = (float*)d_out;

    hipLaunchKernelGGL(vocab_kernel, dim3(VOCAB), dim3(64), 0, stream,
                       embed, W1, b1, W2, b2, ln_g, ln_b, Ws, bs, We, be, ws);
    hipLaunchKernelGGL(gram_kernel, dim3(2), dim3(256), 0, stream, ws);
    hipLaunchKernelGGL(scan_kernel, dim3(BATCH), dim3(128), 0, stream,
                       seq, ws, Wrp, brp, Wo, bo, out);
}

// Round 13
// 201.330 us; speedup vs baseline: 1.3054x; 1.2693x over previous
//
#include <hip/hip_runtime.h>

#define HIDDEN 64
#define HALFD  32
#define VOCAB  64
#define BATCH  256
#define SEQLEN 2048

#define RLF(v, sl) __int_as_float(__builtin_amdgcn_readlane(__float_as_int(v), (sl)))
#define RLI(v, sl) __builtin_amdgcn_readlane((v), (sl))
#define GIX(j,m) (((j)==0?0:(j)==1?7:(j)==2?13:(j)==3?18:(j)==4?22:(j)==5?25:27) + (m) - (j) - 1)
#define OM(m) (((m)*((m)+1))>>1)

// ---------------------------------------------------------------------------
// Kernel 1: per-token vocab tables (unchanged).
//   ws[0    ..2047]  ks_voc [64][32]  (normalized hs)
//   ws[2048 ..4095]  ke_voc [64][32]  (normalized he)
//   ws[4096 ..6143]  vs_voc [64][32]  (raw hs)
//   ws[6144 ..8191]  ve_voc [64][32]  (raw he)
//   ws[8192 ..16383] Gs,Ge [2][64][64]
// ---------------------------------------------------------------------------
__global__ __launch_bounds__(64) void vocab_kernel(
    const float* __restrict__ embed, const float* __restrict__ W1, const float* __restrict__ b1,
    const float* __restrict__ W2, const float* __restrict__ b2,
    const float* __restrict__ ln_g, const float* __restrict__ ln_b,
    const float* __restrict__ Ws, const float* __restrict__ bs,
    const float* __restrict__ We, const float* __restrict__ be,
    float* __restrict__ ws)
{
    const int v = blockIdx.x;
    const int tid = threadIdx.x;

    __shared__ float e_s[64];
    __shared__ float a1_s[128];
    __shared__ float h_s[64];

    e_s[tid] = embed[v * 64 + tid];
    __syncthreads();

    float acc0 = b1[tid], acc1 = b1[tid + 64];
    #pragma unroll 8
    for (int m = 0; m < 64; ++m) {
        float ev = e_s[m];
        acc0 = fmaf(ev, W1[tid * 64 + m], acc0);
        acc1 = fmaf(ev, W1[(tid + 64) * 64 + m], acc1);
    }
    a1_s[tid]      = fmaxf(acc0, 0.0f);
    a1_s[tid + 64] = fmaxf(acc1, 0.0f);
    __syncthreads();

    float ff = b2[tid];
    #pragma unroll 8
    for (int m = 0; m < 128; ++m) ff = fmaf(a1_s[m], W2[tid * 128 + m], ff);
    float x = e_s[tid] + ff;

    float s = x, s2 = x * x;
    #pragma unroll
    for (int off = 32; off >= 1; off >>= 1) {
        s  += __shfl_xor(s,  off, 64);
        s2 += __shfl_xor(s2, off, 64);
    }
    float mu  = s * (1.0f / 64.0f);
    float var = s2 * (1.0f / 64.0f) - mu * mu;
    float hval = (x - mu) * rsqrtf(var + 1e-5f) * ln_g[tid] + ln_b[tid];
    h_s[tid] = hval;
    __syncthreads();

    const int j = tid & 31;
    const bool is_s = tid < 32;
    const float* W = is_s ? Ws : We;
    float acc = is_s ? bs[j] : be[j];
    #pragma unroll 8
    for (int m = 0; m < 64; ++m) acc = fmaf(h_s[m], W[j * 64 + m], acc);

    float n2 = acc * acc;
    #pragma unroll
    for (int off = 16; off >= 1; off >>= 1) n2 += __shfl_xor(n2, off, 64);
    float norm = sqrtf(n2);
    float kn = acc / fmaxf(norm, 1e-12f);

    const int base = v * 32 + j;
    if (is_s) { ws[base]        = kn; ws[4096 + base] = acc; }
    else      { ws[2048 + base] = kn; ws[6144 + base] = acc; }
}

// ---------------------------------------------------------------------------
// Kernel 1b: Gram tables (unchanged).
// ---------------------------------------------------------------------------
__global__ __launch_bounds__(256) void gram_kernel(float* __restrict__ ws)
{
    const int w = blockIdx.x;
    const int tid = threadIdx.x;
    __shared__ float k_s[2048];
    const float* kb = ws + w * 2048;
    for (int i = tid; i < 2048; i += 256) k_s[i] = kb[i];
    __syncthreads();
    const int a  = tid >> 2;
    const int b0 = (tid & 3) << 4;
    float* Gw = ws + 8192 + w * 4096 + a * 64;
    for (int bb = 0; bb < 16; ++bb) {
        const int bcol = b0 + bb;
        float acc = 0.f;
        #pragma unroll
        for (int m = 0; m < 32; ++m) acc = fmaf(k_s[a * 32 + m], k_s[bcol * 32 + m], acc);
        Gw[bcol] = acc;
    }
}

// shared W-build routine (verbatim R9 math)
static __device__ __forceinline__ void build_wpack(
    const int* tj, float fb, float invL, bool is_e, bool is_last, float* Wp,
    const float* __restrict__ Gg)
{
    float f[8];
    #pragma unroll
    for (int j = 0; j < 8; ++j) f[j] = is_e ? (fb + (float)j * invL) : 1.0f;
    if (is_last) f[7] = 0.0f;     // position 2047 is the query, not a write

    float g[28];
    #pragma unroll
    for (int j = 0; j < 7; ++j)
        #pragma unroll
        for (int m = j + 1; m < 8; ++m) g[GIX(j, m)] = Gg[tj[j] * 64 + tj[m]];

    #pragma unroll
    for (int m = 0; m < 8; ++m) {
        float col[8];
        col[m] = f[m];
        #pragma unroll
        for (int j = 6; j >= 0; --j) {
            if (j < m) {
                float acc = 0.0f;
                #pragma unroll
                for (int p = 1; p < 8; ++p)
                    if (p > j && p <= m) acc = fmaf(g[GIX(j, p)], col[p], acc);
                col[j] = -f[j] * acc;
            }
        }
        #pragma unroll
        for (int j = 0; j < 8; ++j)
            if (j <= m) Wp[OM(m) + j] = col[j];
    }
}

struct Chunk {
    int   tokv;      // lane-vector: tok[c*8 + (lane&7)]  (bpermute index; VGPR)
    int   tk[8];     // uniform tokens of this chunk (SGPR via v_readlane)
    float grow[8];   // G[tok_j][lane]  (VMEM-prefetched)
    float W[36];     // packed upper-tri solve matrix (uniform LDS broadcast)
};

// ---------------------------------------------------------------------------
// Kernel 2: R9 structure with four surgical fixes (see R12 post-mortem):
//  (1) Wtab transposed -> Wt4[9][2][256] float4: prologue writes are
//      lane-contiguous (conflict-free; R9's stride-36 writes were 8-way),
//      loop reads are 9 uniform broadcast ds_read_b128 per chunk.
//  (2) Loop tokens from per-lane GLOBAL loads + v_readlane -> SGPR. No token
//      ds_read in the in-order DS queue, no SMEM/lgkm mixing (R12's trap).
//  (3) braw bpermute issued at END of body (right after u update): consumed
//      next body with a full body of slack; it is the last DS op issued.
//  (4) everything else verbatim R9 (algebra validated, absmax 1.2e-7).
// ---------------------------------------------------------------------------
__global__ __launch_bounds__(128) void scan_kernel(
    const int* __restrict__ seq, const float* __restrict__ ws,
    const float* __restrict__ Wrp, const float* __restrict__ brp,
    const float* __restrict__ Wo, const float* __restrict__ bo,
    float* __restrict__ out)
{
    const int b    = blockIdx.x;
    const int tid  = threadIdx.x;        // 0..127
    const int w    = tid >> 6;           // wave: 0 = s-branch, 1 = e-branch
    const int lane = tid & 63;
    const int l7   = lane & 7;
    const bool is_e = (w == 1);

    __shared__ __align__(16) float4 Wt4[9][2][256];   // 72 KB, transposed
    __shared__ __align__(16) int    toklds[SEQLEN];   // 8 KB (prologue only)
    __shared__ float wacc_s[2][64];
    __shared__ float r_s[64];
    __shared__ float t1_s[64];

    const float* Gg = ws + 8192 + w * 4096;
    const int*   sq = seq + b * SEQLEN;

    // ---- stage token sequence (for the W-build prologue) ----
    {
        const int4* sq4 = (const int4*)sq;
        int4* tl = (int4*)toklds;
        #pragma unroll
        for (int i = 0; i < 4; ++i) tl[tid + i * 128] = sq4[tid + i * 128];
    }
    __syncthreads();

    // ---- precompute W packs: lanes parallel over chunks (4 per lane) ----
    {
        const float invL = 1.0f / (float)SEQLEN;
        #pragma unroll
        for (int qq = 0; qq < 4; ++qq) {
            const int c = lane + (qq << 6);
            int tj[8];
            #pragma unroll
            for (int j = 0; j < 8; ++j) tj[j] = toklds[c * 8 + j];
            float Wp[36];
            build_wpack(tj, (float)(8 * c + 1) * invL, invL, is_e, c == 255, Wp, Gg);
            // transposed store: Wt4[i][w][c] — lanes write contiguous float4s
            #pragma unroll
            for (int i = 0; i < 9; ++i)
                Wt4[i][w][c] = make_float4(Wp[4*i], Wp[4*i+1], Wp[4*i+2], Wp[4*i+3]);
        }
    }
    __syncthreads();

    // ---- serial backward sweep ----
    Chunk A, B;
    float u, waccv = 0.0f;

    // prologue: chunk 255 fully, chunk 254 lane-tokens
    A.tokv = sq[2040 + l7];                    // VMEM per-lane
    #pragma unroll
    for (int j = 0; j < 8; ++j) A.tk[j] = RLI(A.tokv, j);
    #pragma unroll
    for (int j = 0; j < 8; ++j) A.grow[j] = Gg[A.tk[j] * 64 + lane];
    #pragma unroll
    for (int i = 0; i < 9; ++i) {
        float4 v = Wt4[i][w][255];
        A.W[4*i] = v.x; A.W[4*i+1] = v.y; A.W[4*i+2] = v.z; A.W[4*i+3] = v.w;
    }
    B.tokv = sq[2032 + l7];
    u = Gg[A.tk[7] * 64 + lane];               // query token = position 2047
    float braw = __shfl(u, A.tokv, 64);        // t-raw for chunk 255

    auto body = [&](Chunk& cur, Chunk& nxt, int c) {
        // ---- chain head: consume braw (issued end of previous body) ----
        float t0 = RLF(braw, 0), t1 = RLF(braw, 1), t2 = RLF(braw, 2), t3 = RLF(braw, 3);
        float t4 = RLF(braw, 4), t5 = RLF(braw, 5), t6 = RLF(braw, 6), t7 = RLF(braw, 7);

        // ---- prefetch chunk c-1 into nxt (all off-chain) ----
        const int cm1 = (c > 0) ? c - 1 : 0;
        const int cm2 = (c > 1) ? c - 2 : 0;
        #pragma unroll
        for (int j = 0; j < 8; ++j) nxt.tk[j] = RLI(nxt.tokv, j);
        #pragma unroll
        for (int j = 0; j < 8; ++j) nxt.grow[j] = Gg[nxt.tk[j] * 64 + lane];
        #pragma unroll
        for (int i = 0; i < 9; ++i) {
            float4 v = Wt4[i][w][cm1];
            nxt.W[4*i] = v.x; nxt.W[4*i+1] = v.y; nxt.W[4*i+2] = v.z; nxt.W[4*i+3] = v.w;
        }
        int tokv2 = sq[cm2 * 8 + l7];          // VMEM per-lane (chunk c-2)

        // ---- s = W t  (36 independent FMAs, depth <= 4) ----
        const float* W = cur.W;
        float s7 = W[35] * t7;
        float s6 = fmaf(W[27], t6, W[34] * t7);
        float s5 = fmaf(W[20], t5, W[26] * t6) + W[33] * t7;
        float s4 = fmaf(W[14], t4, W[19] * t5) + fmaf(W[25], t6, W[32] * t7);
        float s3 = fmaf(W[9],  t3, W[13] * t4) + fmaf(W[18], t5, fmaf(W[24], t6, W[31] * t7));
        float s2 = fmaf(W[5],  t2, W[8]  * t3) + fmaf(W[12], t4, W[17] * t5) + fmaf(W[23], t6, W[30] * t7);
        float s1 = fmaf(W[2],  t1, W[4]  * t2) + fmaf(W[7],  t3, W[11] * t4) + fmaf(W[16], t5, fmaf(W[22], t6, W[29] * t7));
        float s0 = fmaf(W[0],  t0, W[1]  * t1) + fmaf(W[3],  t2, W[6]  * t3) + fmaf(W[10], t4, W[15] * t5) + fmaf(W[21], t6, W[28] * t7);

        // ---- u[a] -= sum_j s_j * G[tok_j][a] ----
        float dA = fmaf(cur.grow[0], s0, fmaf(cur.grow[1], s1, fmaf(cur.grow[2], s2, cur.grow[3] * s3)));
        float dB = fmaf(cur.grow[4], s4, fmaf(cur.grow[5], s5, fmaf(cur.grow[6], s6, cur.grow[7] * s7)));
        u -= (dA + dB);

        // ---- issue next braw IMMEDIATELY (full body of slack) ----
        braw = __shfl(u, nxt.tokv, 64);

        // ---- wacc[tok_j] += s_j  (lane = token; off-chain) ----
        waccv += (lane == cur.tk[0]) ? s0 : 0.0f;
        waccv += (lane == cur.tk[1]) ? s1 : 0.0f;
        waccv += (lane == cur.tk[2]) ? s2 : 0.0f;
        waccv += (lane == cur.tk[3]) ? s3 : 0.0f;
        waccv += (lane == cur.tk[4]) ? s4 : 0.0f;
        waccv += (lane == cur.tk[5]) ? s5 : 0.0f;
        waccv += (lane == cur.tk[6]) ? s6 : 0.0f;
        waccv += (lane == cur.tk[7]) ? s7 : 0.0f;

        cur.tokv = tokv2;   // retire cur; becomes chunk c-2's lane tokens
    };

    for (int c = 255; c >= 1; c -= 2) {
        body(A, B, c);
        body(B, A, c - 1);
    }

    wacc_s[w][lane] = waccv;
    __syncthreads();

    // r[w2][rho] = sum_tok wacc[w2][tok] * v[w2][tok][rho]  (v from global ws)
    if (tid < 64) {
        const int w2  = tid >> 5;
        const int rho = tid & 31;
        const float* vv = ws + 4096 + w2 * 2048;
        const float* wa = &wacc_s[w2][0];
        float acc = 0.0f;
        #pragma unroll 8
        for (int tok = 0; tok < 64; ++tok) acc = fmaf(wa[tok], vv[tok * 32 + rho], acc);
        r_s[tid] = acc;
    }
    __syncthreads();

    // out = (r @ Wrp.T + brp) @ Wo.T + bo
    if (tid < 64) {
        float acc = brp[tid];
        #pragma unroll 8
        for (int m = 0; m < 64; ++m) acc = fmaf(Wrp[tid * 64 + m], r_s[m], acc);
        t1_s[tid] = acc;
    }
    __syncthreads();
    if (tid < 64) {
        float acc = bo[tid];
        #pragma unroll 8
        for (int m = 0; m < 64; ++m) acc = fmaf(Wo[tid * 64 + m], t1_s[m], acc);
        out[b * 64 + tid] = acc;
    }
}

extern "C" void kernel_launch(void* const* d_in, const int* in_sizes, int n_in,
                              void* d_out, int out_size, void* d_ws, size_t ws_size,
                              hipStream_t stream)
{
    const int*   seq   = (const int*)  d_in[0];
    const float* embed = (const float*)d_in[1];
    const float* W1    = (const float*)d_in[2];
    const float* b1    = (const float*)d_in[3];
    const float* W2    = (const float*)d_in[4];
    const float* b2    = (const float*)d_in[5];
    const float* ln_g  = (const float*)d_in[6];
    const float* ln_b  = (const float*)d_in[7];
    const float* Ws    = (const float*)d_in[8];
    const float* bs    = (const float*)d_in[9];
    const float* We    = (const float*)d_in[10];
    const float* be    = (const float*)d_in[11];
    const float* Wrp   = (const float*)d_in[12];
    const float* brp   = (const float*)d_in[13];
    const float* Wo    = (const float*)d_in[14];
    const float* bo    = (const float*)d_in[15];
    float* ws  = (float*)d_ws;
    float* out = (float*)d_out;

    hipLaunchKernelGGL(vocab_kernel, dim3(VOCAB), dim3(64), 0, stream,
                       embed, W1, b1, W2, b2, ln_g, ln_b, Ws, bs, We, be, ws);
    hipLaunchKernelGGL(gram_kernel, dim3(2), dim3(256), 0, stream, ws);
    hipLaunchKernelGGL(scan_kernel, dim3(BATCH), dim3(128), 0, stream,
                       seq, ws, Wrp, brp, Wo, bo, out);
}